// Round 1
// baseline (22004.028 us; speedup 1.0000x reference)
//
#include <hip/hip_runtime.h>
#include <cstdint>
#include <cmath>

#define BB 64
#define TT 512
#define NI 256
#define HH 1024
#define NO 512
#define NSTEPS 100
#define KT 64
#define NBLK 256
#define NTHR 512
#define NCTR 64

// ---- persistent device-global state (module-owned; NOT in d_ws) ----
__device__ unsigned g_arr[(NCTR + 1) * 32];  // 64 arrival lines (128B apart) + flag line
__device__ __align__(16) float g_hA[HH * BB];
__device__ __align__(16) float g_hB[HH * BB];
__device__ __align__(16) float g_cst[HH * BB];
__device__ __align__(16) float g_dsum[4 * HH];
__device__ __align__(16) float g_logits[NO * BB];
__device__ __align__(16) float g_xt[TT * NI * BB];   // x transposed to [t][k][b]

__device__ __forceinline__ float sigf(float x) { return 1.0f / (1.0f + expf(-x)); }

// agent-scope write-through store: lands at the LLC (coherence point) before
// the vmcnt(0) that __syncthreads emits in bar_arrive -> release side is
// exactly the previously-verified scheme.
__device__ __forceinline__ void stc1(float* p, float v) {
  union { float f; unsigned u; } c; c.f = v;
  __hip_atomic_store((unsigned*)p, c.u, __ATOMIC_RELAXED, __HIP_MEMORY_SCOPE_AGENT);
}

__device__ __forceinline__ void bar_arrive(int blk) {
  __syncthreads();
  if (threadIdx.x == 0) {
    __hip_atomic_fetch_add(&g_arr[(blk & (NCTR - 1)) * 32], 1u,
                           __ATOMIC_RELAXED, __HIP_MEMORY_SCOPE_AGENT);
  }
}

// Grid barrier wait + ACQUIRE at agent scope.
// The acquire fence emits buffer_inv (invalidate clean L1/L2 lines) so that
// subsequent PLAIN cached loads observe the producers' LLC (stc1) writes.
// Dirty lines (block-private g_cst) are preserved by inv. After the fence,
// h reads are ordinary dwordx4 loads: the 32 blocks of an XCD share each h
// line through their L2 (32x less LLC traffic, L2-hit latency).
__device__ __forceinline__ void bar_wait(int blk, unsigned n) {
  if (blk == 0) {
    if (threadIdx.x < 64) {            // wave-cooperative counter poll
      for (;;) {
        unsigned v = __hip_atomic_load(&g_arr[threadIdx.x * 32],
                                       __ATOMIC_RELAXED, __HIP_MEMORY_SCOPE_AGENT);
        #pragma unroll
        for (int off = 32; off; off >>= 1) v += __shfl_xor(v, off);
        if (v >= n * NBLK) break;
        __builtin_amdgcn_s_sleep(1);
      }
      if (threadIdx.x == 0)
        __hip_atomic_store(&g_arr[NCTR * 32], n, __ATOMIC_RELAXED,
                           __HIP_MEMORY_SCOPE_AGENT);
    }
  } else if (threadIdx.x == 0) {
    while (__hip_atomic_load(&g_arr[NCTR * 32], __ATOMIC_RELAXED,
                             __HIP_MEMORY_SCOPE_AGENT) < n)
      __builtin_amdgcn_s_sleep(1);
  }
  __syncthreads();
  __builtin_amdgcn_fence(__ATOMIC_ACQUIRE, "agent");
}

__global__ void reset_counter() {
  if (threadIdx.x <= NCTR) g_arr[threadIdx.x * 32] = 0u;
}

// A tile: 4096 floats = 512 threads x 2 float4 stripes (dwordx4, plain cached)
#define LOAD_A(asrc) \
  { ah0 = *(const float4*)&(asrc)[tid * 4]; \
    ah1 = *(const float4*)&(asrc)[tid * 4 + 2048]; }

// Store into XOR-swizzled As: 16B slot index is XORed with (row>>1)&3 so the
// 4 kk-quadrants of a wave land on disjoint bank groups on read.
#define STORE_A(bufi) \
  { float* ab = &AsF[(bufi) * 4096]; \
    *(float4*)&ab[a_st] = ah0; \
    *(float4*)&ab[a_st + 2048] = ah1; }

#define FMA_CHUNK(bufi, wch) \
  _Pragma("unroll") \
  for (int kk2 = 0; kk2 < 2; ++kk2) { \
    const int kk = kt2 * 2 + kk2; \
    const float* abp = &AsF[(bufi) * 4096 + (kk << 6)]; \
    const float* wbp = &Wall[((wch) << 10) + (kk << 4)]; \
    float4 a0 = *(const float4*)(abp + slA0); \
    float4 a1 = *(const float4*)(abp + slA1); \
    float4 w0 = *(const float4*)(wbp + slW0); \
    float4 w1 = *(const float4*)(wbp + slW1); \
    float av8[8] = {a0.x, a0.y, a0.z, a0.w, a1.x, a1.y, a1.z, a1.w}; \
    float wv8[8] = {w0.x, w0.y, w0.z, w0.w, w1.x, w1.y, w1.z, w1.w}; \
    _Pragma("unroll") for (int r = 0; r < 8; ++r) \
      _Pragma("unroll") for (int c = 0; c < 8; ++c) \
        acc[r][c] = fmaf(wv8[r], av8[c], acc[r][c]); \
  }

__global__ void __launch_bounds__(NTHR, 1)
seq2seq_kernel(const float* __restrict__ xin,
               const float* __restrict__ eWih, const float* __restrict__ eWhh,
               const float* __restrict__ ebih, const float* __restrict__ ebhh,
               const float* __restrict__ dWih, const float* __restrict__ dWhh,
               const float* __restrict__ dbih, const float* __restrict__ dbhh,
               const float* __restrict__ fcW,  const float* __restrict__ fcb,
               int* __restrict__ out)
{
  // LDS budget: 32K As + 80K Wall + 36.1K Gp + 4.4K misc = 152.4 KiB (<160)
  __shared__ __align__(16) float AsF[2 * 4096];       // double-buffered A, swizzled
  __shared__ __align__(16) float Wall[20 * KT * 16];  // step-invariant W^T stash
  __shared__ __align__(16) float Gp[8][17][68];       // K-split partials (8 groups)
  __shared__ float avals[8][BB];
  __shared__ int   aidx[8][BB];
  __shared__ float ptok[BB];

  const int tid = threadIdx.x;
  const int blk = blockIdx.x;
  unsigned sync_no = 0;

  const int wv  = tid >> 6;
  const int ln  = tid & 63;
  const int hi  = ln >> 5;
  const int l5  = ln & 31;
  const int kt2 = (((wv << 1) | (l5 >> 4)) << 1) | hi;   // 0..31 reg K-group
  const int rg  = (l5 >> 3) & 1;        // row group (x8)
  const int cg  = l5 & 7;               // batch group (x8)
  const int jj2 = (tid >> 6) & 3;
  const int cb  = tid & 63;
  const int j2  = blk * 4 + jj2;
  const int ktd = tid >> 4;             // D2: 0..31 K-split
  const int cgd = tid & 15;
  // swizzled 16B-slot offsets (quadrant spread): f(kk) = (kk>>1)&3 = kt2&3
  const int sq   = kt2 & 3;
  const int slA0 = ((cg * 2)     ^ sq) << 2;
  const int slA1 = ((cg * 2 + 1) ^ sq) << 2;
  const int slW0 = ((rg * 2)     ^ sq) << 2;
  const int slW1 = ((rg * 2 + 1) ^ sq) << 2;
  const int slD  = (cgd ^ (ktd & 3)) << 2;
  const int a_st = ((tid >> 4) << 6) | (((tid & 15) ^ ((tid >> 5) & 3)) << 2);
  float* const Gpd = &Gp[0][0][0];      // D2 alias: [32][4][68]

  // ---------------- init ----------------
  {
    if (tid < 256) {
      int idx = blk * 256 + tid;        // block-owned h/c slice
      stc1(&g_hA[idx], 0.0f);           // h: cross-block -> LLC
      g_cst[idx] = 0.0f;                // c: block-private, stays dirty in L2
    }
    int rr = blk * 16 + (tid >> 5);
    int l32 = tid & 31;
    const float* wrp = dWih + (size_t)rr * NO;
    float s = 0.0f;
    for (int k = l32; k < NO; k += 32) s += wrp[k];
    for (int off = 16; off; off >>= 1) s += __shfl_down(s, off, 32);
    if (l32 == 0) stc1(&g_dsum[rr], s);
    for (int w = blk * NTHR + tid; w < TT * NI * BB; w += NBLK * NTHR) {
      int b = w & 63;
      int tk = w >> 6;
      int k = tk & (NI - 1);
      int t = tk >> 8;
      stc1(&g_xt[w], xin[((size_t)b * TT + t) * NI + k]);
    }
    // encoder W stash: 16 rows x 1280 cols, consumer layout [c][16r], swizzled
    for (int r2 = 0; r2 < 16; ++r2) {
      const int growr = (r2 >> 2) * HH + blk * 4 + (r2 & 3);
      for (int c0 = 0; c0 < NI + HH; c0 += NTHR) {
        const int c = c0 + tid;
        if (c < NI + HH) {
          const float w = (c < NI) ? eWih[(size_t)growr * NI + c]
                                   : eWhh[(size_t)growr * HH + (c - NI)];
          Wall[c * 16 + ((((r2 >> 2) ^ ((c >> 1) & 3)) << 2) | (r2 & 3))] = w;
        }
      }
    }
  }
  const float be0 = ebih[j2]          + ebhh[j2];
  const float be1 = ebih[HH + j2]     + ebhh[HH + j2];
  const float be2 = ebih[2 * HH + j2] + ebhh[2 * HH + j2];
  const float be3 = ebih[3 * HH + j2] + ebhh[3 * HH + j2];
  bar_arrive(blk); ++sync_no; bar_wait(blk, sync_no);

  const float* hc = g_hA;
  float* hn = g_hB;

  float4 ah0, ah1;
  LOAD_A(g_xt);                          // t=0 chunk 0 prologue (static x)

  // ================ encoder: 512 steps ================
  for (int t = 0; t < TT; ++t) {
    float acc[8][8];
    #pragma unroll
    for (int r = 0; r < 8; ++r)
      #pragma unroll
      for (int c = 0; c < 8; ++c) acc[r][c] = 0.0f;

    STORE_A(0);
    #pragma unroll 2
    for (int ch = 0; ch < 20; ++ch) {
      const int buf = ch & 1;
      // chunks 0..2 touch only static x -> run pre-wait; first h load is
      // issued at ch==3, so wait (and invalidate) just before it.
      if (ch == 3) bar_wait(blk, sync_no);
      if (ch + 1 < 20) {
        const int c1 = ch + 1;
        const float* asrc = (c1 < 4)
            ? g_xt + ((size_t)t * NI + c1 * KT) * BB
            : hc + (size_t)(c1 * KT - NI) * BB;   // plain dwordx4, L2-shared
        LOAD_A(asrc);
      }
      __syncthreads();
      FMA_CHUNK(buf, ch);
      if (ch + 1 < 20) STORE_A(buf ^ 1);
    }
    // merge K-groups in-register: lanes {ln, ln^16, ln^32, ln^48} share (rg,cg)
    #pragma unroll
    for (int r = 0; r < 8; ++r)
      #pragma unroll
      for (int c = 0; c < 8; ++c) {
        acc[r][c] += __shfl_xor(acc[r][c], 32);
        acc[r][c] += __shfl_xor(acc[r][c], 16);
      }
    __syncthreads();
    if (ln < 16) {
      #pragma unroll
      for (int r = 0; r < 8; ++r) {
        float4 v0 = {acc[r][0], acc[r][1], acc[r][2], acc[r][3]};
        float4 v1 = {acc[r][4], acc[r][5], acc[r][6], acc[r][7]};
        *(float4*)&Gp[wv][rg * 8 + r][cg * 8]     = v0;
        *(float4*)&Gp[wv][rg * 8 + r][cg * 8 + 4] = v1;
      }
    }
    __syncthreads();
    if (tid < 256) {
      float gsum[4];
      #pragma unroll
      for (int g = 0; g < 4; ++g) {
        const int rt = g * 4 + jj2;
        float ssum = 0.0f;
        #pragma unroll
        for (int q = 0; q < 8; ++q) ssum += Gp[q][rt][cb];
        gsum[g] = ssum;
      }
      float pi = gsum[0] + be0;
      float pf = gsum[1] + be1;
      float pg = gsum[2] + be2;
      float po = gsum[3] + be3;
      float co = g_cst[(size_t)j2 * BB + cb];
      float cn = sigf(pf) * co + sigf(pi) * tanhf(pg);
      float hv = sigf(po) * tanhf(cn);
      g_cst[(size_t)j2 * BB + cb] = cn;
      stc1(&hn[(size_t)j2 * BB + cb], hv);
    }
    // prefetch next step chunk 0 (static x) before arriving
    {
      const int tn = (t + 1 < TT) ? t + 1 : t;
      LOAD_A(g_xt + (size_t)tn * NI * BB);
    }
    bar_arrive(blk); ++sync_no;
    { float* tmp = (float*)hc; hc = hn; hn = tmp; }
  }
  if (tid < BB) ptok[tid] = 0.0f;
  bar_wait(blk, sync_no);   // final encoder h visible; covers ptok init too

  // ---- decoder W stash: dWhh slice (overwrites encoder stash) + fcW ----
  for (int r2 = 0; r2 < 16; ++r2) {
    const int growr = (r2 >> 2) * HH + blk * 4 + (r2 & 3);
    for (int c0 = 0; c0 < HH; c0 += NTHR) {
      const int c = c0 + tid;
      const float w = dWhh[(size_t)growr * HH + c];
      Wall[c * 16 + ((((r2 >> 2) ^ ((c >> 1) & 3)) << 2) | (r2 & 3))] = w;
    }
  }
  if (blk < 128) {
    for (int e = tid; e < 4096; e += NTHR) {   // fcW: 4 rows x 1024, [c][4r]
      const int rr = e >> 10;
      const int c = e & 1023;
      Wall[16384 + c * 4 + rr] = fcW[(size_t)(blk * 4 + rr) * HH + c];
    }
  }
  __syncthreads();

  // ================ decoder: 100 steps ================
  const float bd0 = dbih[j2]          + dbhh[j2];
  const float bd1 = dbih[HH + j2]     + dbhh[HH + j2];
  const float bd2 = dbih[2 * HH + j2] + dbhh[2 * HH + j2];
  const float bd3 = dbih[3 * HH + j2] + dbhh[3 * HH + j2];
  const float ds0 = g_dsum[j2];
  const float ds1 = g_dsum[HH + j2];
  const float ds2 = g_dsum[2 * HH + j2];
  const float ds3 = g_dsum[3 * HH + j2];
  LOAD_A(hc);                               // D1 s=0 chunk-0 prologue

  for (int s = 0; s < NSTEPS; ++s) {
    // ---- D1: LSTM cell, K = HH ----
    float acc[8][8];
    #pragma unroll
    for (int r = 0; r < 8; ++r)
      #pragma unroll
      for (int c = 0; c < 8; ++c) acc[r][c] = 0.0f;

    STORE_A(0);
    #pragma unroll 2
    for (int ch = 0; ch < 16; ++ch) {
      const int buf = ch & 1;
      if (ch + 1 < 16) LOAD_A(hc + (size_t)(ch + 1) * KT * BB);
      __syncthreads();
      FMA_CHUNK(buf, ch);
      if (ch + 1 < 16) STORE_A(buf ^ 1);
    }
    #pragma unroll
    for (int r = 0; r < 8; ++r)
      #pragma unroll
      for (int c = 0; c < 8; ++c) {
        acc[r][c] += __shfl_xor(acc[r][c], 32);
        acc[r][c] += __shfl_xor(acc[r][c], 16);
      }
    __syncthreads();
    if (ln < 16) {
      #pragma unroll
      for (int r = 0; r < 8; ++r) {
        float4 v0 = {acc[r][0], acc[r][1], acc[r][2], acc[r][3]};
        float4 v1 = {acc[r][4], acc[r][5], acc[r][6], acc[r][7]};
        *(float4*)&Gp[wv][rg * 8 + r][cg * 8]     = v0;
        *(float4*)&Gp[wv][rg * 8 + r][cg * 8 + 4] = v1;
      }
    }
    __syncthreads();
    if (tid < 256) {
      float gsum[4];
      #pragma unroll
      for (int g = 0; g < 4; ++g) {
        const int rt = g * 4 + jj2;
        float ssum = 0.0f;
        #pragma unroll
        for (int q = 0; q < 8; ++q) ssum += Gp[q][rt][cb];
        gsum[g] = ssum;
      }
      float tk = ptok[cb];
      float pi = gsum[0] + bd0 + tk * ds0;
      float pf = gsum[1] + bd1 + tk * ds1;
      float pg = gsum[2] + bd2 + tk * ds2;
      float po = gsum[3] + bd3 + tk * ds3;
      float co = g_cst[(size_t)j2 * BB + cb];
      float cn = sigf(pf) * co + sigf(pi) * tanhf(pg);
      float hv = sigf(po) * tanhf(cn);
      g_cst[(size_t)j2 * BB + cb] = cn;
      stc1(&hn[(size_t)j2 * BB + cb], hv);
    }
    bar_arrive(blk); ++sync_no; bar_wait(blk, sync_no);
    { float* tmp = (float*)hc; hc = hn; hn = tmp; }   // hc = new h

    // ---- D2: logits = h @ fc_W^T + fc_b (blocks 0..127, 4 o-rows each) ----
    if (blk < 128) {
      float facc[4][4];
      #pragma unroll
      for (int r = 0; r < 4; ++r)
        #pragma unroll
        for (int c = 0; c < 4; ++c) facc[r][c] = 0.0f;

      LOAD_A(hc);
      STORE_A(0);
      #pragma unroll 2
      for (int ch = 0; ch < 16; ++ch) {
        const int buf = ch & 1;
        if (ch + 1 < 16) LOAD_A(hc + (size_t)(ch + 1) * KT * BB);
        __syncthreads();
        #pragma unroll
        for (int kk2 = 0; kk2 < 2; ++kk2) {
          const int kk = ktd * 2 + kk2;
          float4 a = *(const float4*)&AsF[buf * 4096 + (kk << 6) + slD];
          float4 w = *(const float4*)&Wall[16384 + (((ch << 6) + kk) << 2)];
          float av4[4] = {a.x, a.y, a.z, a.w};
          float wv4[4] = {w.x, w.y, w.z, w.w};
          #pragma unroll
          for (int r = 0; r < 4; ++r)
            #pragma unroll
            for (int c = 0; c < 4; ++c)
              facc[r][c] = fmaf(wv4[r], av4[c], facc[r][c]);
        }
        if (ch + 1 < 16) STORE_A(buf ^ 1);
      }
      __syncthreads();
      #pragma unroll
      for (int r = 0; r < 4; ++r) {
        float4 v = {facc[r][0], facc[r][1], facc[r][2], facc[r][3]};
        *(float4*)&Gpd[ktd * 272 + r * 68 + cgd * 4] = v;
      }
      __syncthreads();
      if (tid < 256) {
        const int oo = tid >> 6, ob = tid & 63;
        float ssum = 0.0f;
        #pragma unroll
        for (int q = 0; q < 32; ++q) ssum += Gpd[q * 272 + oo * 68 + ob];
        const int o = blk * 4 + oo;
        stc1(&g_logits[(size_t)o * BB + ob], ssum + fcb[o]);
      }
    }
    // prefetch next D1 chunk 0 (hc unchanged during D2/argmax)
    LOAD_A(hc);
    bar_arrive(blk); ++sync_no; bar_wait(blk, sync_no);

    // ---- argmax (redundant per block; first-index tie-break) ----
    {
      const int q = tid >> 6, b = tid & 63;
      float bv = -3.402823466e38f; int bo = 0;
      #pragma unroll
      for (int g = 0; g < 4; ++g) {
        float lv[16];
        #pragma unroll
        for (int i = 0; i < 16; ++i)
          lv[i] = g_logits[(size_t)(q * 64 + g * 16 + i) * BB + b];
        #pragma unroll
        for (int i = 0; i < 16; ++i)
          if (lv[i] > bv) { bv = lv[i]; bo = q * 64 + g * 16 + i; }
      }
      avals[q][b] = bv; aidx[q][b] = bo;
    }
    __syncthreads();
    if (tid < BB) {
      float bv = avals[0][tid]; int bo = aidx[0][tid];
      #pragma unroll
      for (int q = 1; q < 8; ++q)
        if (avals[q][tid] > bv) { bv = avals[q][tid]; bo = aidx[q][tid]; }
      ptok[tid] = (float)bo;
      if (blk == 0) out[(size_t)tid * NSTEPS + s] = bo;   // int32 tokens
    }
    __syncthreads();
  }
}

extern "C" void kernel_launch(void* const* d_in, const int* in_sizes, int n_in,
                              void* d_out, int out_size, void* d_ws, size_t ws_size,
                              hipStream_t stream) {
  (void)in_sizes; (void)n_in; (void)out_size; (void)d_ws; (void)ws_size;
  const float* xin  = (const float*)d_in[0];
  const float* eWih = (const float*)d_in[1];
  const float* eWhh = (const float*)d_in[2];
  const float* ebih = (const float*)d_in[3];
  const float* ebhh = (const float*)d_in[4];
  const float* dWih = (const float*)d_in[5];
  const float* dWhh = (const float*)d_in[6];
  const float* dbih = (const float*)d_in[7];
  const float* dbhh = (const float*)d_in[8];
  const float* fcW  = (const float*)d_in[9];
  const float* fcb  = (const float*)d_in[10];
  int* out = (int*)d_out;

  reset_counter<<<1, 128, 0, stream>>>();
  seq2seq_kernel<<<NBLK, NTHR, 0, stream>>>(
      xin, eWih, eWhh, ebih, ebhh, dWih, dWhh, dbih, dbhh, fcW, fcb, out);
}

// Round 2
// 13162.424 us; speedup vs baseline: 1.6717x; 1.6717x over previous
//
#include <hip/hip_runtime.h>
#include <cstdint>
#include <cmath>

#define BB 64
#define TT 512
#define NI 256
#define HH 1024
#define NO 512
#define NSTEPS 100
#define KT 64
#define NBLK 256
#define NTHR 512
#define NCTR 64
#define APAD 68                 // padded As row stride (floats): bank offsets {0,8,16,24}
#define ASTRIDE (KT * APAD)     // 4352 floats per As buffer

// ---- persistent device-global state (module-owned; NOT in d_ws) ----
__device__ unsigned g_arr[(NCTR + 1) * 32];  // 64 arrival lines (128B apart)
__device__ __align__(16) float g_hA[HH * BB];
__device__ __align__(16) float g_hB[HH * BB];
__device__ __align__(16) float g_cst[HH * BB];
__device__ __align__(16) float g_dsum[4 * HH];
__device__ __align__(16) float g_logits[NO * BB];
__device__ __align__(16) float g_xt[TT * NI * BB];   // x transposed to [t][k][b]

__device__ __forceinline__ float sigf(float x) { return 1.0f / (1.0f + expf(-x)); }

// ---- agent-coherent (sc1) access via intrinsics: compiler-tracked waitcnts ----
__device__ __forceinline__ float2 ldh2(const float* p) {
  unsigned long long u = __hip_atomic_load((const unsigned long long*)p,
                                           __ATOMIC_RELAXED, __HIP_MEMORY_SCOPE_AGENT);
  union { unsigned long long u; float2 f; } c; c.u = u; return c.f;
}
__device__ __forceinline__ float ldc1(const float* p) {
  unsigned u = __hip_atomic_load((const unsigned*)p,
                                 __ATOMIC_RELAXED, __HIP_MEMORY_SCOPE_AGENT);
  union { unsigned u; float f; } c; c.u = u; return c.f;
}
__device__ __forceinline__ void stc1(float* p, float v) {
  union { float f; unsigned u; } c; c.f = v;
  __hip_atomic_store((unsigned*)p, c.u, __ATOMIC_RELAXED, __HIP_MEMORY_SCOPE_AGENT);
}

// Fence-free grid barrier (round-0 proven release semantics: sc1 stores are
// drained by the compiler's vmcnt(0) before s_barrier in bar_arrive; consumers
// read mutable data with sc1 loads, so no cache maintenance is needed).
__device__ __forceinline__ void bar_arrive(int blk) {
  __syncthreads();
  if (threadIdx.x == 0) {
    __hip_atomic_fetch_add(&g_arr[(blk & (NCTR - 1)) * 32], 1u,
                           __ATOMIC_RELAXED, __HIP_MEMORY_SCOPE_AGENT);
  }
}

// Distributed wait: every block's wave 0 sums the 64 counters directly
// (removes the central-flag LLC propagation hop of the round-0 scheme).
__device__ __forceinline__ void bar_wait(unsigned n) {
  if (threadIdx.x < 64) {
    for (;;) {
      unsigned v = __hip_atomic_load(&g_arr[threadIdx.x * 32],
                                     __ATOMIC_RELAXED, __HIP_MEMORY_SCOPE_AGENT);
      #pragma unroll
      for (int off = 32; off; off >>= 1) v += __shfl_xor(v, off);
      if (v >= n * NBLK) break;
      __builtin_amdgcn_s_sleep(1);
    }
  }
  __syncthreads();
}

__global__ void reset_counter() {
  if (threadIdx.x <= NCTR) g_arr[threadIdx.x * 32] = 0u;
}

// ---- A-tile loads: 4096 floats = 512 threads x 4 float2 stripes ----
#define LOADA_X(d0, d1, d2, d3, src) \
  { d0 = *(const float2*)&(src)[tid * 2]; \
    d1 = *(const float2*)&(src)[tid * 2 + 1024]; \
    d2 = *(const float2*)&(src)[tid * 2 + 2048]; \
    d3 = *(const float2*)&(src)[tid * 2 + 3072]; }
#define LOADA_H(d0, d1, d2, d3, src) \
  { d0 = ldh2(&(src)[tid * 2]); \
    d1 = ldh2(&(src)[tid * 2 + 1024]); \
    d2 = ldh2(&(src)[tid * 2 + 2048]); \
    d3 = ldh2(&(src)[tid * 2 + 3072]); }
#define LOADW2(w0, w1, wsrc, ld, k) \
  { const float* wp = (wsrc) + (size_t)grow0 * (ld) + (k) + kkl; \
    w0 = wp[0]; w1 = wp[(size_t)(ld)]; }

// Store into padded As (row = e>>6 at stride APAD) + Wt staging.
#define STORE_AW(bufi, a0, a1, a2, a3, w0v, w1v) \
  { float* ab = &AsF[(bufi) * ASTRIDE]; \
    *(float2*)&ab[pa0]        = a0; \
    *(float2*)&ab[pa0 + 1088] = a1; \
    *(float2*)&ab[pa0 + 2176] = a2; \
    *(float2*)&ab[pa0 + 3264] = a3; \
    float2 w2; w2.x = w0v; w2.y = w1v; \
    *(float2*)&Wt[bufi][kkl][r0] = w2; }

#define STORE_AF(bufi, a0, a1, a2, a3, fwv) \
  { float* ab = &AsF[(bufi) * ASTRIDE]; \
    *(float2*)&ab[pa0]        = a0; \
    *(float2*)&ab[pa0 + 1088] = a1; \
    *(float2*)&ab[pa0 + 2176] = a2; \
    *(float2*)&ab[pa0 + 3264] = a3; \
    Wt[bufi][kkl][jj2] = fwv; }

#define FMA_CHUNK(bufi) \
  _Pragma("unroll") \
  for (int kk2 = 0; kk2 < 2; ++kk2) { \
    const int kk = kt2 * 2 + kk2; \
    const float* abp = &AsF[(bufi) * ASTRIDE + kk * APAD]; \
    float4 a0 = *(const float4*)(abp + cg * 8); \
    float4 a1 = *(const float4*)(abp + cg * 8 + 4); \
    float4 w0 = *(const float4*)&Wt[bufi][kk][rg * 8]; \
    float4 w1 = *(const float4*)&Wt[bufi][kk][rg * 8 + 4]; \
    float av8[8] = {a0.x, a0.y, a0.z, a0.w, a1.x, a1.y, a1.z, a1.w}; \
    float wv8[8] = {w0.x, w0.y, w0.z, w0.w, w1.x, w1.y, w1.z, w1.w}; \
    _Pragma("unroll") for (int r = 0; r < 8; ++r) \
      _Pragma("unroll") for (int c = 0; c < 8; ++c) \
        acc[r][c] = fmaf(wv8[r], av8[c], acc[r][c]); \
  }

#define FMA_D2(bufi) \
  _Pragma("unroll") \
  for (int kk2 = 0; kk2 < 2; ++kk2) { \
    const int kk = ktd * 2 + kk2; \
    float4 a = *(const float4*)&AsF[(bufi) * ASTRIDE + kk * APAD + cgd * 4]; \
    float4 w = *(const float4*)&Wt[bufi][kk][0]; \
    float av4[4] = {a.x, a.y, a.z, a.w}; \
    float wv4[4] = {w.x, w.y, w.z, w.w}; \
    _Pragma("unroll") for (int r = 0; r < 4; ++r) \
      _Pragma("unroll") for (int c = 0; c < 4; ++c) \
        facc[r][c] = fmaf(wv4[r], av4[c], facc[r][c]); \
  }

// Encoder virtual-chunk load: v<20 = this step (x for v<4, h after); v>=20 wraps
// to next step's x chunks (always dependency-free) => fully wrapped pipeline.
#define ENC_LOAD(d0, d1, d2, d3, w0, w1, v) \
  { const int vv = (v); \
    if (vv < 20) { \
      if (vv < 4) { \
        LOADA_X(d0, d1, d2, d3, g_xt + ((size_t)t * NI + vv * KT) * BB); \
        LOADW2(w0, w1, eWih, NI, vv * KT); \
      } else { \
        LOADA_H(d0, d1, d2, d3, hc + (size_t)(vv * KT - NI) * BB); \
        LOADW2(w0, w1, eWhh, HH, vv * KT - NI); \
      } \
    } else if (t + 1 < TT) { \
      LOADA_X(d0, d1, d2, d3, g_xt + ((size_t)(t + 1) * NI + (vv - 20) * KT) * BB); \
      LOADW2(w0, w1, eWih, NI, (vv - 20) * KT); \
    } }

__global__ void __launch_bounds__(NTHR, 1)
seq2seq_kernel(const float* __restrict__ xin,
               const float* __restrict__ eWih, const float* __restrict__ eWhh,
               const float* __restrict__ ebih, const float* __restrict__ ebhh,
               const float* __restrict__ dWih, const float* __restrict__ dWhh,
               const float* __restrict__ dbih, const float* __restrict__ dbhh,
               const float* __restrict__ fcW,  const float* __restrict__ fcb,
               int* __restrict__ out)
{
  // LDS: As 34.0K + Wt 10.0K + Gp 36.1K + misc 4.4K = 84.5 KiB
  __shared__ __align__(16) float AsF[2 * ASTRIDE];  // double-buffered A, padded rows
  __shared__ __align__(16) float Wt[2][KT][20];     // double-buffered W^T staging
  __shared__ __align__(16) float Gp[8][17][68];     // per-wave K-partials
  __shared__ float avals[8][BB];
  __shared__ int   aidx[8][BB];
  __shared__ float ptok[BB];

  const int tid = threadIdx.x;
  const int blk = blockIdx.x;
  unsigned sync_no = 0;

  const int wv  = tid >> 6;
  const int ln  = tid & 63;
  const int hi  = ln >> 5;
  const int l5  = ln & 31;
  const int kt2 = (((wv << 1) | (l5 >> 4)) << 1) | hi;   // 0..31 reg K-group
  const int rg  = (l5 >> 3) & 1;        // row group (x8)
  const int cg  = l5 & 7;               // batch group (x8)
  const int jj2 = (tid >> 6) & 3;
  const int cb  = tid & 63;
  const int j2  = blk * 4 + jj2;
  const int r0  = wv * 2;               // W staging cols
  const int kkl = ln;
  const int grow0 = ((r0 >> 2) * HH + blk * 4 + (r0 & 3));
  const int ktd = tid >> 4;             // D2: 0..31 K-split
  const int cgd = tid & 15;
  const int pa0 = (tid >> 5) * APAD + (tid & 31) * 2;   // padded store base
  float* const Gpd = &Gp[0][0][0];      // D2 alias: [32][4][68]

  // ---------------- init ----------------
  {
    if (tid < 256) {
      int idx = blk * 256 + tid;        // block-owned h/c slice
      stc1(&g_hA[idx], 0.0f);           // h: coherent (cross-block read)
      g_cst[idx] = 0.0f;                // c: block-private, cached
    }
    int rr = blk * 16 + (tid >> 5);
    int l32 = tid & 31;
    const float* wrp = dWih + (size_t)rr * NO;
    float s = 0.0f;
    for (int k = l32; k < NO; k += 32) s += wrp[k];
    for (int off = 16; off; off >>= 1) s += __shfl_down(s, off, 32);
    if (l32 == 0) stc1(&g_dsum[rr], s);
    // x transpose with COALESCED reads (xin is [b][t][k]; read linear,
    // scatter 4B sc1 stores fire-and-forget into the LLC)
    for (size_t w = (size_t)blk * NTHR + tid; w < (size_t)TT * NI * BB;
         w += (size_t)NBLK * NTHR) {
      int k = (int)(w & (NI - 1));
      int t = (int)((w >> 8) & (TT - 1));
      int b = (int)(w >> 17);
      stc1(&g_xt[((size_t)t * NI + k) * BB + b], xin[w]);
    }
  }
  const float be0 = ebih[j2]          + ebhh[j2];
  const float be1 = ebih[HH + j2]     + ebhh[HH + j2];
  const float be2 = ebih[2 * HH + j2] + ebhh[2 * HH + j2];
  const float be3 = ebih[3 * HH + j2] + ebhh[3 * HH + j2];
  bar_arrive(blk); ++sync_no; bar_wait(sync_no);

  const float* hc = g_hA;
  float* hn = g_hB;

  float2 aP0, aP1, aP2, aP3, aQ0, aQ1, aQ2, aQ3;
  float wP0, wP1, wQ0, wQ1;

  // encoder pipeline prologue: chunk0 -> LDS, chunk1 -> P, chunk2 -> Q
  LOADA_X(aP0, aP1, aP2, aP3, g_xt);
  LOADW2(wP0, wP1, eWih, NI, 0);
  STORE_AW(0, aP0, aP1, aP2, aP3, wP0, wP1);
  LOADA_X(aP0, aP1, aP2, aP3, g_xt + (size_t)KT * BB);
  LOADW2(wP0, wP1, eWih, NI, KT);
  LOADA_X(aQ0, aQ1, aQ2, aQ3, g_xt + (size_t)2 * KT * BB);
  LOADW2(wQ0, wQ1, eWih, NI, 2 * KT);

  // ================ encoder: 512 steps (wrapped depth-2 pipeline) ================
  for (int t = 0; t < TT; ++t) {
    float acc[8][8];
    #pragma unroll
    for (int r = 0; r < 8; ++r)
      #pragma unroll
      for (int c = 0; c < 8; ++c) acc[r][c] = 0.0f;

    for (int c2 = 0; c2 < 10; ++c2) {
      // even chunk ch = 2*c2 (buf 0); store odd chunk from P; load into P
      __syncthreads();
      FMA_CHUNK(0);
      STORE_AW(1, aP0, aP1, aP2, aP3, wP0, wP1);
      ENC_LOAD(aP0, aP1, aP2, aP3, wP0, wP1, 2 * c2 + 3);
      // odd chunk ch = 2*c2+1 (buf 1); store even chunk from Q; load into Q
      __syncthreads();
      FMA_CHUNK(1);
      STORE_AW(0, aQ0, aQ1, aQ2, aQ3, wQ0, wQ1);
      if (c2 == 0) bar_wait(sync_no);   // h(t) ready before first h load (v=4)
      ENC_LOAD(aQ0, aQ1, aQ2, aQ3, wQ0, wQ1, 2 * c2 + 4);
    }
    // merge the 4 lane-copies (kt2 quadrants) in-register
    #pragma unroll
    for (int r = 0; r < 8; ++r)
      #pragma unroll
      for (int c = 0; c < 8; ++c) {
        acc[r][c] += __shfl_xor(acc[r][c], 32);
        acc[r][c] += __shfl_xor(acc[r][c], 16);
      }
    __syncthreads();
    if (ln < 16) {
      #pragma unroll
      for (int r = 0; r < 8; ++r) {
        float4 v0 = {acc[r][0], acc[r][1], acc[r][2], acc[r][3]};
        float4 v1 = {acc[r][4], acc[r][5], acc[r][6], acc[r][7]};
        *(float4*)&Gp[wv][rg * 8 + r][cg * 8]     = v0;
        *(float4*)&Gp[wv][rg * 8 + r][cg * 8 + 4] = v1;
      }
    }
    __syncthreads();
    if (tid < 256) {
      float gsum[4];
      #pragma unroll
      for (int g = 0; g < 4; ++g) {
        const int rt = g * 4 + jj2;
        float ssum = 0.0f;
        #pragma unroll
        for (int q = 0; q < 8; ++q) ssum += Gp[q][rt][cb];
        gsum[g] = ssum;
      }
      float pi = gsum[0] + be0;
      float pf = gsum[1] + be1;
      float pg = gsum[2] + be2;
      float po = gsum[3] + be3;
      float co = g_cst[(size_t)j2 * BB + cb];
      float cn = sigf(pf) * co + sigf(pi) * tanhf(pg);
      float hv = sigf(po) * tanhf(cn);
      g_cst[(size_t)j2 * BB + cb] = cn;
      stc1(&hn[(size_t)j2 * BB + cb], hv);
    }
    bar_arrive(blk); ++sync_no;
    { float* tmp = (float*)hc; hc = hn; hn = tmp; }
  }
  if (tid < BB) ptok[tid] = 0.0f;
  bar_wait(sync_no);   // final encoder h visible; covers ptok init too

  // ================ decoder: 100 steps ================
  const float bd0 = dbih[j2]          + dbhh[j2];
  const float bd1 = dbih[HH + j2]     + dbhh[HH + j2];
  const float bd2 = dbih[2 * HH + j2] + dbhh[2 * HH + j2];
  const float bd3 = dbih[3 * HH + j2] + dbhh[3 * HH + j2];
  const float ds0 = g_dsum[j2];
  const float ds1 = g_dsum[HH + j2];
  const float ds2 = g_dsum[2 * HH + j2];
  const float ds3 = g_dsum[3 * HH + j2];
  // D1 s=0 chunk-0 preload (final h valid after the bar_wait above)
  LOADA_H(aP0, aP1, aP2, aP3, hc);
  LOADW2(wP0, wP1, dWhh, HH, 0);

  for (int s = 0; s < NSTEPS; ++s) {
    // ---- D1: LSTM cell, K = HH (depth-2 pipeline) ----
    float acc[8][8];
    #pragma unroll
    for (int r = 0; r < 8; ++r)
      #pragma unroll
      for (int c = 0; c < 8; ++c) acc[r][c] = 0.0f;

    STORE_AW(0, aP0, aP1, aP2, aP3, wP0, wP1);            // chunk0
    LOADA_H(aP0, aP1, aP2, aP3, hc + (size_t)KT * BB);    // chunk1 -> P
    LOADW2(wP0, wP1, dWhh, HH, KT);
    LOADA_H(aQ0, aQ1, aQ2, aQ3, hc + (size_t)2 * KT * BB); // chunk2 -> Q
    LOADW2(wQ0, wQ1, dWhh, HH, 2 * KT);
    for (int c2 = 0; c2 < 8; ++c2) {
      __syncthreads();
      FMA_CHUNK(0);
      STORE_AW(1, aP0, aP1, aP2, aP3, wP0, wP1);          // chunk 2c2+1
      if (2 * c2 + 3 < 16) {
        LOADA_H(aP0, aP1, aP2, aP3, hc + (size_t)(2 * c2 + 3) * KT * BB);
        LOADW2(wP0, wP1, dWhh, HH, (2 * c2 + 3) * KT);
      }
      __syncthreads();
      FMA_CHUNK(1);
      if (2 * c2 + 2 < 16) STORE_AW(0, aQ0, aQ1, aQ2, aQ3, wQ0, wQ1);
      if (2 * c2 + 4 < 16) {
        LOADA_H(aQ0, aQ1, aQ2, aQ3, hc + (size_t)(2 * c2 + 4) * KT * BB);
        LOADW2(wQ0, wQ1, dWhh, HH, (2 * c2 + 4) * KT);
      }
    }
    #pragma unroll
    for (int r = 0; r < 8; ++r)
      #pragma unroll
      for (int c = 0; c < 8; ++c) {
        acc[r][c] += __shfl_xor(acc[r][c], 32);
        acc[r][c] += __shfl_xor(acc[r][c], 16);
      }
    __syncthreads();
    if (ln < 16) {
      #pragma unroll
      for (int r = 0; r < 8; ++r) {
        float4 v0 = {acc[r][0], acc[r][1], acc[r][2], acc[r][3]};
        float4 v1 = {acc[r][4], acc[r][5], acc[r][6], acc[r][7]};
        *(float4*)&Gp[wv][rg * 8 + r][cg * 8]     = v0;
        *(float4*)&Gp[wv][rg * 8 + r][cg * 8 + 4] = v1;
      }
    }
    __syncthreads();
    if (tid < 256) {
      float gsum[4];
      #pragma unroll
      for (int g = 0; g < 4; ++g) {
        const int rt = g * 4 + jj2;
        float ssum = 0.0f;
        #pragma unroll
        for (int q = 0; q < 8; ++q) ssum += Gp[q][rt][cb];
        gsum[g] = ssum;
      }
      float tk = ptok[cb];
      float pi = gsum[0] + bd0 + tk * ds0;
      float pf = gsum[1] + bd1 + tk * ds1;
      float pg = gsum[2] + bd2 + tk * ds2;
      float po = gsum[3] + bd3 + tk * ds3;
      float co = g_cst[(size_t)j2 * BB + cb];
      float cn = sigf(pf) * co + sigf(pi) * tanhf(pg);
      float hv = sigf(po) * tanhf(cn);
      g_cst[(size_t)j2 * BB + cb] = cn;
      stc1(&hn[(size_t)j2 * BB + cb], hv);
    }
    bar_arrive(blk); ++sync_no; bar_wait(sync_no);
    { float* tmp = (float*)hc; hc = hn; hn = tmp; }   // hc = new h

    // ---- D2: logits = h @ fc_W^T + fc_b (blocks 0..127, 4 o-rows each) ----
    if (blk < 128) {
      float facc[4][4];
      #pragma unroll
      for (int r = 0; r < 4; ++r)
        #pragma unroll
        for (int c = 0; c < 4; ++c) facc[r][c] = 0.0f;

      const size_t fb = (size_t)(blk * 4 + jj2) * HH + kkl;
      float fwP, fwQ;
      LOADA_H(aP0, aP1, aP2, aP3, hc);
      fwP = fcW[fb];
      STORE_AF(0, aP0, aP1, aP2, aP3, fwP);               // chunk0
      LOADA_H(aP0, aP1, aP2, aP3, hc + (size_t)KT * BB);  // chunk1 -> P
      fwP = fcW[fb + KT];
      LOADA_H(aQ0, aQ1, aQ2, aQ3, hc + (size_t)2 * KT * BB); // chunk2 -> Q
      fwQ = fcW[fb + 2 * KT];
      for (int c2 = 0; c2 < 8; ++c2) {
        __syncthreads();
        FMA_D2(0);
        STORE_AF(1, aP0, aP1, aP2, aP3, fwP);
        if (2 * c2 + 3 < 16) {
          LOADA_H(aP0, aP1, aP2, aP3, hc + (size_t)(2 * c2 + 3) * KT * BB);
          fwP = fcW[fb + (2 * c2 + 3) * KT];
        }
        __syncthreads();
        FMA_D2(1);
        if (2 * c2 + 2 < 16) STORE_AF(0, aQ0, aQ1, aQ2, aQ3, fwQ);
        if (2 * c2 + 4 < 16) {
          LOADA_H(aQ0, aQ1, aQ2, aQ3, hc + (size_t)(2 * c2 + 4) * KT * BB);
          fwQ = fcW[fb + (2 * c2 + 4) * KT];
        }
      }
      __syncthreads();
      #pragma unroll
      for (int r = 0; r < 4; ++r) {
        float4 v = {facc[r][0], facc[r][1], facc[r][2], facc[r][3]};
        *(float4*)&Gpd[ktd * 272 + r * 68 + cgd * 4] = v;
      }
      __syncthreads();
      if (tid < 256) {
        const int oo = tid >> 6, ob = tid & 63;
        float ssum = 0.0f;
        #pragma unroll
        for (int q = 0; q < 32; ++q) ssum += Gpd[q * 272 + oo * 68 + ob];
        const int o = blk * 4 + oo;
        stc1(&g_logits[(size_t)o * BB + ob], ssum + fcb[o]);
      }
    }
    // prefetch next D1 chunk 0 (hc unchanged during D2/argmax) — latency
    // hides under the logits barrier + argmax phase
    LOADA_H(aP0, aP1, aP2, aP3, hc);
    LOADW2(wP0, wP1, dWhh, HH, 0);
    bar_arrive(blk); ++sync_no; bar_wait(sync_no);

    // ---- argmax (redundant per block; first-index tie-break) ----
    {
      const int q = tid >> 6, b = tid & 63;
      float bv = -3.402823466e38f; int bo = 0;
      #pragma unroll
      for (int g = 0; g < 4; ++g) {
        float lv[16];
        #pragma unroll
        for (int i = 0; i < 16; ++i)
          lv[i] = ldc1(&g_logits[(size_t)(q * 64 + g * 16 + i) * BB + b]);
        #pragma unroll
        for (int i = 0; i < 16; ++i)
          if (lv[i] > bv) { bv = lv[i]; bo = q * 64 + g * 16 + i; }
      }
      avals[q][b] = bv; aidx[q][b] = bo;
    }
    __syncthreads();
    if (tid < BB) {
      float bv = avals[0][tid]; int bo = aidx[0][tid];
      #pragma unroll
      for (int q = 1; q < 8; ++q)
        if (avals[q][tid] > bv) { bv = avals[q][tid]; bo = aidx[q][tid]; }
      ptok[tid] = (float)bo;
      if (blk == 0) out[(size_t)tid * NSTEPS + s] = bo;   // int32 tokens
    }
    __syncthreads();
  }
}

extern "C" void kernel_launch(void* const* d_in, const int* in_sizes, int n_in,
                              void* d_out, int out_size, void* d_ws, size_t ws_size,
                              hipStream_t stream) {
  (void)in_sizes; (void)n_in; (void)out_size; (void)d_ws; (void)ws_size;
  const float* xin  = (const float*)d_in[0];
  const float* eWih = (const float*)d_in[1];
  const float* eWhh = (const float*)d_in[2];
  const float* ebih = (const float*)d_in[3];
  const float* ebhh = (const float*)d_in[4];
  const float* dWih = (const float*)d_in[5];
  const float* dWhh = (const float*)d_in[6];
  const float* dbih = (const float*)d_in[7];
  const float* dbhh = (const float*)d_in[8];
  const float* fcW  = (const float*)d_in[9];
  const float* fcb  = (const float*)d_in[10];
  int* out = (int*)d_out;

  reset_counter<<<1, 128, 0, stream>>>();
  seq2seq_kernel<<<NBLK, NTHR, 0, stream>>>(
      xin, eWih, eWhh, ebih, ebhh, dWih, dWhh, dbih, dbhh, fcW, fcb, out);
}

// Round 3
// 12626.040 us; speedup vs baseline: 1.7427x; 1.0425x over previous
//
#include <hip/hip_runtime.h>
#include <cstdint>
#include <cmath>

#define BB 64
#define TT 512
#define NI 256
#define HH 1024
#define NO 512
#define NSTEPS 100
#define KT 64
#define NBLK 256
#define NTHR 512
#define NCTR 64
#define WD2 16384                    // fcW stash base (floats) inside Wall

// ---- persistent device-global state (module-owned; NOT in d_ws) ----
__device__ unsigned g_arr[(NCTR + 1) * 32];  // 64 arrival lines (128B apart)
__device__ __align__(16) float g_hA[HH * BB];
__device__ __align__(16) float g_hB[HH * BB];
__device__ __align__(16) float g_cst[HH * BB];
__device__ __align__(16) float g_dsum[4 * HH];
__device__ __align__(16) float g_logits[NO * BB];
__device__ __align__(16) float g_xt[TT * NI * BB];   // x transposed to [t][k][b]

__device__ __forceinline__ float sigf(float x) { return 1.0f / (1.0f + expf(-x)); }

// ---- agent-coherent (sc1) access via intrinsics ----
__device__ __forceinline__ float2 ldh2(const float* p) {
  unsigned long long u = __hip_atomic_load((const unsigned long long*)p,
                                           __ATOMIC_RELAXED, __HIP_MEMORY_SCOPE_AGENT);
  union { unsigned long long u; float2 f; } c; c.u = u; return c.f;
}
__device__ __forceinline__ float ldc1(const float* p) {
  unsigned u = __hip_atomic_load((const unsigned*)p,
                                 __ATOMIC_RELAXED, __HIP_MEMORY_SCOPE_AGENT);
  union { unsigned u; float f; } c; c.u = u; return c.f;
}
__device__ __forceinline__ void stc1(float* p, float v) {
  union { float f; unsigned u; } c; c.f = v;
  __hip_atomic_store((unsigned*)p, c.u, __ATOMIC_RELAXED, __HIP_MEMORY_SCOPE_AGENT);
}

// release: sc1 stores drained by the vmcnt(0) before s_barrier in bar_arrive.
__device__ __forceinline__ void bar_arrive(int blk) {
  __syncthreads();
  if (threadIdx.x == 0) {
    __hip_atomic_fetch_add(&g_arr[(blk & (NCTR - 1)) * 32], 1u,
                           __ATOMIC_RELAXED, __HIP_MEMORY_SCOPE_AGENT);
  }
}

// wave-decoupled wait: wave 0 polls the 64 LLC counters; waves 1..7 spin on an
// LDS flag (workgroup acquire/release) -> no __syncthreads, no convoy.
__device__ __forceinline__ void bar_wait(unsigned n, unsigned* bf) {
  const int ln = threadIdx.x & 63;
  if ((threadIdx.x >> 6) == 0) {
    for (;;) {
      unsigned v = __hip_atomic_load(&g_arr[ln * 32],
                                     __ATOMIC_RELAXED, __HIP_MEMORY_SCOPE_AGENT);
      #pragma unroll
      for (int off = 32; off; off >>= 1) v += __shfl_xor(v, off);
      if (v >= n * NBLK) break;
      __builtin_amdgcn_s_sleep(1);
    }
    if (ln == 0)
      __hip_atomic_store(bf, n, __ATOMIC_RELEASE, __HIP_MEMORY_SCOPE_WORKGROUP);
  } else {
    while (__hip_atomic_load(bf, __ATOMIC_ACQUIRE, __HIP_MEMORY_SCOPE_WORKGROUP) < n)
      __builtin_amdgcn_s_sleep(2);
  }
}

__global__ void reset_counter() {
  if (threadIdx.x <= NCTR) g_arr[threadIdx.x * 32] = 0u;
}

struct RSlot { float4 a, b; };

// ---- per-wave A staging: wave wv owns K-rows 8wv..8wv+7 of each chunk ----
// lane ln: rows lrow and lrow+4, 16B col lc4. LDS layout: 8 rows x 64 floats,
// 16B slot XOR-swizzled by (row>>1) -> FMA reads are bank-uniform (4-cyc min).
#define LOADC_X(R, src) \
  { const float* p_ = (src) + (size_t)((8 * wv + lrow) * BB) + lc4 * 4; \
    (R).a = *(const float4*)p_; \
    (R).b = *(const float4*)(p_ + 4 * BB); }

#define LOADC_H(R, src) \
  { const float* p_ = (src) + (size_t)((8 * wv + lrow) * BB) + lc4 * 4; \
    float2 u0_ = ldh2(p_),        u1_ = ldh2(p_ + 2); \
    float2 u2_ = ldh2(p_ + 4*BB), u3_ = ldh2(p_ + 4*BB + 2); \
    (R).a = make_float4(u0_.x, u0_.y, u1_.x, u1_.y); \
    (R).b = make_float4(u2_.x, u2_.y, u3_.x, u3_.y); }

#define STOREC(bufi, R) \
  { float* b_ = &Su[AsW + (bufi) * 512]; \
    *(float4*)&b_[st0] = (R).a; \
    *(float4*)&b_[st1] = (R).b; }

#define FMA_CHUNK(bufi, ch) \
  { const float* ab_ = &Su[AsW + (bufi) * 512 + row2 * 64]; \
    const float* wp_ = &Wall[(ch) * 1024 + wb]; \
    _Pragma("unroll") \
    for (int kk2 = 0; kk2 < 2; ++kk2) { \
      float4 a0 = *(const float4*)(ab_ + kk2 * 64 + a0c); \
      float4 a1 = *(const float4*)(ab_ + kk2 * 64 + a1c); \
      float4 w0 = *(const float4*)(wp_ + kk2 * 64); \
      float4 w1 = *(const float4*)(wp_ + kk2 * 64 + 4); \
      float av_[8] = {a0.x, a0.y, a0.z, a0.w, a1.x, a1.y, a1.z, a1.w}; \
      float wv_[8] = {w0.x, w0.y, w0.z, w0.w, w1.x, w1.y, w1.z, w1.w}; \
      _Pragma("unroll") for (int r = 0; r < 8; ++r) \
        _Pragma("unroll") for (int c = 0; c < 8; ++c) \
          acc[r][c] = fmaf(wv_[r], av_[c], acc[r][c]); \
    } }

// D2: register-direct (no LDS). Lane loads exactly rows {2*lrow, 2*lrow+1}.
#define LOADD2(R, src, ch) \
  { const float* p_ = (src) + (size_t)(((ch) * KT + 8 * wv + 2 * lrow) * BB) + lc4 * 4; \
    float2 u0_ = ldh2(p_),      u1_ = ldh2(p_ + 2); \
    float2 u2_ = ldh2(p_ + BB), u3_ = ldh2(p_ + BB + 2); \
    (R).a = make_float4(u0_.x, u0_.y, u1_.x, u1_.y); \
    (R).b = make_float4(u2_.x, u2_.y, u3_.x, u3_.y); }

#define FMA_D2(R, ch) \
  { const float* wp_ = &Wall[WD2 + (ch) * 256 + wv * 32 + lrow * 4]; \
    float4 w0 = *(const float4*)(wp_); \
    float4 w1 = *(const float4*)(wp_ + 16); \
    float a_[4] = {(R).a.x, (R).a.y, (R).a.z, (R).a.w}; \
    float b2_[4] = {(R).b.x, (R).b.y, (R).b.z, (R).b.w}; \
    float w0_[4] = {w0.x, w0.y, w0.z, w0.w}; \
    float w1_[4] = {w1.x, w1.y, w1.z, w1.w}; \
    _Pragma("unroll") for (int r = 0; r < 4; ++r) \
      _Pragma("unroll") for (int c = 0; c < 4; ++c) { \
        facc[r][c] = fmaf(w0_[r], a_[c], facc[r][c]); \
        facc[r][c] = fmaf(w1_[r], b2_[c], facc[r][c]); \
      } }

#define GPX(q, rt, cb2) Su[(q) * 1156 + (rt) * 68 + (cb2)]

__global__ void __launch_bounds__(NTHR, 1)
seq2seq_kernel(const float* __restrict__ xin,
               const float* __restrict__ eWih, const float* __restrict__ eWhh,
               const float* __restrict__ ebih, const float* __restrict__ ebhh,
               const float* __restrict__ dWih, const float* __restrict__ dWhh,
               const float* __restrict__ dbih, const float* __restrict__ dbhh,
               const float* __restrict__ fcW,  const float* __restrict__ fcb,
               int* __restrict__ out)
{
  // LDS: Su (As 8x1024 U Gp 9248) 36.1K + Wall 80K + misc 4.3K = 120.4 KiB
  __shared__ __align__(16) float Su[9248];      // union: per-wave As | Gp partials
  __shared__ __align__(16) float Wall[20480];   // resident W (per-wave layout)
  __shared__ float avals[8][BB];
  __shared__ int   aidx[8][BB];
  __shared__ float ptok[BB];
  __shared__ unsigned bflag;

  const int tid = threadIdx.x;
  const int blk = blockIdx.x;
  unsigned sync_no = 0;

  const int wv  = tid >> 6;
  const int ln  = tid & 63;
  const int hi  = ln >> 5;
  const int l5  = ln & 31;
  const int jl  = ((l5 >> 4) << 1) | hi;   // 0..3: wave-local K row-pair
  const int rg  = (l5 >> 3) & 1;
  const int cg  = l5 & 7;
  const int lrow = ln >> 4;                // 0..3 staging row
  const int lc4  = ln & 15;                // 16B col
  const int jj2 = (tid >> 6) & 3;
  const int cb  = tid & 63;
  const int j2  = blk * 4 + jj2;
  const int ktd = 4 * wv + lrow;           // D2 K-group 0..31
  const int AsW = wv * 1024;
  const int st0 = lrow * 64 + ((lc4 ^ (lrow >> 1)) << 2);
  const int st1 = (lrow + 4) * 64 + ((lc4 ^ ((lrow >> 1) + 2)) << 2);
  const int row2 = 2 * jl;
  const int a0c = (((cg << 1) ^ jl) << 2);
  const int a1c = ((((cg << 1) | 1) ^ jl) << 2);
  const int wb  = wv * 128 + (((jl << 1) | rg) << 3);

  // ---------------- init ----------------
  {
    if (tid == 0) bflag = 0u;
    if (tid < 256) {
      int idx = blk * 256 + tid;
      stc1(&g_hA[idx], 0.0f);           // h: coherent (cross-block)
      g_cst[idx] = 0.0f;                // c: block-private, cached
    }
    int rr = blk * 16 + (tid >> 5);
    int l32 = tid & 31;
    const float* wrp = dWih + (size_t)rr * NO;
    float s = 0.0f;
    for (int k = l32; k < NO; k += 32) s += wrp[k];
    for (int off = 16; off; off >>= 1) s += __shfl_down(s, off, 32);
    if (l32 == 0) stc1(&g_dsum[rr], s);
    // x transpose: coalesced reads, scattered sc1 stores
    for (size_t w = (size_t)blk * NTHR + tid; w < (size_t)TT * NI * BB;
         w += (size_t)NBLK * NTHR) {
      int k = (int)(w & (NI - 1));
      int t = (int)((w >> 8) & (TT - 1));
      int b = (int)(w >> 17);
      stc1(&g_xt[((size_t)t * NI + k) * BB + b], xin[w]);
    }
    // encoder W stash: per-wave layout [ch][wv][kk2][(jl<<1)|rg][half][4]
    for (int c = 0; c < 16; ++c) {
      const int gr = (c >> 2) * HH + blk * 4 + (c & 3);
      const int rgc = c >> 3, rc = c & 7, half = rc >> 2, q = rc & 3;
      for (int k = tid; k < NI + HH; k += NTHR) {
        const float w = (k < NI) ? eWih[(size_t)gr * NI + k]
                                 : eWhh[(size_t)gr * HH + (k - NI)];
        const int ch = k >> 6, kl = k & 63, wt = kl >> 3, lo = kl & 7;
        Wall[ch * 1024 + wt * 128 + (lo & 1) * 64 +
             ((((lo >> 1) << 1) | rgc) << 3) + half * 4 + q] = w;
      }
    }
  }
  const float be0 = ebih[j2]          + ebhh[j2];
  const float be1 = ebih[HH + j2]     + ebhh[HH + j2];
  const float be2 = ebih[2 * HH + j2] + ebhh[2 * HH + j2];
  const float be3 = ebih[3 * HH + j2] + ebhh[3 * HH + j2];
  bar_arrive(blk); ++sync_no; bar_wait(sync_no, &bflag);

  const float* hc = g_hA;
  float* hn = g_hB;

  RSlot Rs[4];
  // prologue: x(t=0) chunks 0,1,2
  LOADC_X(Rs[0], g_xt);
  LOADC_X(Rs[1], g_xt + (size_t)KT * BB);
  LOADC_X(Rs[2], g_xt + (size_t)2 * KT * BB);

  // ================ encoder: 512 steps, wave-private pipeline ================
  for (int t = 0; t < TT; ++t) {
    float acc[8][8];
    #pragma unroll
    for (int r = 0; r < 8; ++r)
      #pragma unroll
      for (int c = 0; c < 8; ++c) acc[r][c] = 0.0f;

    STOREC(0, Rs[0]);                                       // chunk 0
    // cc=0
    STOREC(1, Rs[1]);
    LOADC_X(Rs[3], g_xt + ((size_t)t * NI + 3 * KT) * BB);
    FMA_CHUNK(0, 0);
    // cc=1 : h(t-1) becomes safe to read here
    bar_wait(sync_no, &bflag);
    STOREC(0, Rs[2]);
    LOADC_H(Rs[0], hc);
    LOADC_H(Rs[1], hc + (size_t)KT * BB);
    FMA_CHUNK(1, 1);
    // cc=2
    STOREC(1, Rs[3]);
    LOADC_H(Rs[2], hc + (size_t)2 * KT * BB);
    FMA_CHUNK(0, 2);
    // cc=3
    STOREC(0, Rs[0]);                                       // chunk 4 (h0)
    LOADC_H(Rs[3], hc + (size_t)3 * KT * BB);
    FMA_CHUNK(1, 3);
    // cc=4..15
    for (int cb4 = 0; cb4 < 3; ++cb4) {
      const int cc = 4 + cb4 * 4;
      STOREC(1, Rs[1]); LOADC_H(Rs[0], hc + (size_t)(cc    ) * KT * BB); FMA_CHUNK(0, cc);
      STOREC(0, Rs[2]); LOADC_H(Rs[1], hc + (size_t)(cc + 1) * KT * BB); FMA_CHUNK(1, cc + 1);
      STOREC(1, Rs[3]); LOADC_H(Rs[2], hc + (size_t)(cc + 2) * KT * BB); FMA_CHUNK(0, cc + 2);
      STOREC(0, Rs[0]); LOADC_H(Rs[3], hc + (size_t)(cc + 3) * KT * BB); FMA_CHUNK(1, cc + 3);
    }
    // cc=16..19 (wrap loads to next step's x chunks)
    {
      const int tn = (t + 1 < TT) ? t + 1 : t;
      STOREC(1, Rs[1]); LOADC_X(Rs[0], g_xt + (size_t)tn * NI * BB);            FMA_CHUNK(0, 16);
      STOREC(0, Rs[2]); LOADC_X(Rs[1], g_xt + ((size_t)tn * NI + KT) * BB);     FMA_CHUNK(1, 17);
      STOREC(1, Rs[3]); LOADC_X(Rs[2], g_xt + ((size_t)tn * NI + 2 * KT) * BB); FMA_CHUNK(0, 18);
      FMA_CHUNK(1, 19);
    }
    // merge the 4 wave-local K-groups in-register
    #pragma unroll
    for (int r = 0; r < 8; ++r)
      #pragma unroll
      for (int c = 0; c < 8; ++c) {
        acc[r][c] += __shfl_xor(acc[r][c], 32);
        acc[r][c] += __shfl_xor(acc[r][c], 16);
      }
    __syncthreads();                     // all As reads done -> Gp may overwrite
    if (ln < 16) {
      #pragma unroll
      for (int r = 0; r < 8; ++r) {
        float4 v0 = {acc[r][0], acc[r][1], acc[r][2], acc[r][3]};
        float4 v1 = {acc[r][4], acc[r][5], acc[r][6], acc[r][7]};
        *(float4*)&GPX(wv, rg * 8 + r, cg * 8)     = v0;
        *(float4*)&GPX(wv, rg * 8 + r, cg * 8 + 4) = v1;
      }
    }
    __syncthreads();
    if (tid < 256) {
      float gsum[4];
      #pragma unroll
      for (int g = 0; g < 4; ++g) {
        const int rt = g * 4 + jj2;
        float ssum = 0.0f;
        #pragma unroll
        for (int q = 0; q < 8; ++q) ssum += GPX(q, rt, cb);
        gsum[g] = ssum;
      }
      float pi = gsum[0] + be0;
      float pf = gsum[1] + be1;
      float pg = gsum[2] + be2;
      float po = gsum[3] + be3;
      float co = g_cst[(size_t)j2 * BB + cb];
      float cn = sigf(pf) * co + sigf(pi) * tanhf(pg);
      float hv = sigf(po) * tanhf(cn);
      g_cst[(size_t)j2 * BB + cb] = cn;
      stc1(&hn[(size_t)j2 * BB + cb], hv);
    }
    bar_arrive(blk); ++sync_no;
    { float* tmp = (float*)hc; hc = hn; hn = tmp; }
  }
  if (tid < BB) ptok[tid] = 0.0f;
  bar_wait(sync_no, &bflag);             // final encoder h visible

  // ---- decoder W stash: dWhh (chunks 0..15) + fcW (blocks 0..127) ----
  // (encoder FMAs all completed before the last bar_arrive's __syncthreads)
  LOADC_H(Rs[0], hc);                    // D1 s=0 prefetch, overlaps stash fill
  LOADC_H(Rs[1], hc + (size_t)KT * BB);
  LOADC_H(Rs[2], hc + (size_t)2 * KT * BB);
  LOADC_H(Rs[3], hc + (size_t)3 * KT * BB);
  for (int c = 0; c < 16; ++c) {
    const int gr = (c >> 2) * HH + blk * 4 + (c & 3);
    const int rgc = c >> 3, rc = c & 7, half = rc >> 2, q = rc & 3;
    for (int k = tid; k < HH; k += NTHR) {
      const float w = dWhh[(size_t)gr * HH + k];
      const int ch = k >> 6, kl = k & 63, wt = kl >> 3, lo = kl & 7;
      Wall[ch * 1024 + wt * 128 + (lo & 1) * 64 +
           ((((lo >> 1) << 1) | rgc) << 3) + half * 4 + q] = w;
    }
  }
  if (blk < 128) {
    for (int k = tid; k < HH; k += NTHR) {
      const int ch = k >> 6, kl = k & 63, wt = kl >> 3, lo = kl & 7;
      const int base = WD2 + ch * 256 + wt * 32 + (lo & 1) * 16 + (lo >> 1) * 4;
      #pragma unroll
      for (int oo = 0; oo < 4; ++oo)
        Wall[base + oo] = fcW[(size_t)(blk * 4 + oo) * HH + k];
    }
  }
  __syncthreads();                       // Wall ready for all waves

  // ================ decoder: 100 steps ================
  const float bd0 = dbih[j2]          + dbhh[j2];
  const float bd1 = dbih[HH + j2]     + dbhh[HH + j2];
  const float bd2 = dbih[2 * HH + j2] + dbhh[2 * HH + j2];
  const float bd3 = dbih[3 * HH + j2] + dbhh[3 * HH + j2];
  const float ds0 = g_dsum[j2];
  const float ds1 = g_dsum[HH + j2];
  const float ds2 = g_dsum[2 * HH + j2];
  const float ds3 = g_dsum[3 * HH + j2];

  for (int s = 0; s < NSTEPS; ++s) {
    // ---- D1: LSTM cell, K = HH, 16 chunks, wave-private pipeline ----
    float acc[8][8];
    #pragma unroll
    for (int r = 0; r < 8; ++r)
      #pragma unroll
      for (int c = 0; c < 8; ++c) acc[r][c] = 0.0f;

    STOREC(0, Rs[0]);                                       // chunk 0
    STOREC(1, Rs[1]); LOADC_H(Rs[0], hc + (size_t)4 * KT * BB); FMA_CHUNK(0, 0);
    STOREC(0, Rs[2]); LOADC_H(Rs[1], hc + (size_t)5 * KT * BB); FMA_CHUNK(1, 1);
    STOREC(1, Rs[3]); LOADC_H(Rs[2], hc + (size_t)6 * KT * BB); FMA_CHUNK(0, 2);
    STOREC(0, Rs[0]); LOADC_H(Rs[3], hc + (size_t)7 * KT * BB); FMA_CHUNK(1, 3);
    for (int cb4 = 0; cb4 < 2; ++cb4) {
      const int cc = 4 + cb4 * 4;
      STOREC(1, Rs[1]); LOADC_H(Rs[0], hc + (size_t)(cc + 4) * KT * BB); FMA_CHUNK(0, cc);
      STOREC(0, Rs[2]); LOADC_H(Rs[1], hc + (size_t)(cc + 5) * KT * BB); FMA_CHUNK(1, cc + 1);
      STOREC(1, Rs[3]); LOADC_H(Rs[2], hc + (size_t)(cc + 6) * KT * BB); FMA_CHUNK(0, cc + 2);
      STOREC(0, Rs[0]); LOADC_H(Rs[3], hc + (size_t)(cc + 7) * KT * BB); FMA_CHUNK(1, cc + 3);
    }
    STOREC(1, Rs[1]); FMA_CHUNK(0, 12);
    STOREC(0, Rs[2]); FMA_CHUNK(1, 13);
    STOREC(1, Rs[3]); FMA_CHUNK(0, 14);
    FMA_CHUNK(1, 15);

    #pragma unroll
    for (int r = 0; r < 8; ++r)
      #pragma unroll
      for (int c = 0; c < 8; ++c) {
        acc[r][c] += __shfl_xor(acc[r][c], 32);
        acc[r][c] += __shfl_xor(acc[r][c], 16);
      }
    __syncthreads();
    if (ln < 16) {
      #pragma unroll
      for (int r = 0; r < 8; ++r) {
        float4 v0 = {acc[r][0], acc[r][1], acc[r][2], acc[r][3]};
        float4 v1 = {acc[r][4], acc[r][5], acc[r][6], acc[r][7]};
        *(float4*)&GPX(wv, rg * 8 + r, cg * 8)     = v0;
        *(float4*)&GPX(wv, rg * 8 + r, cg * 8 + 4) = v1;
      }
    }
    __syncthreads();
    if (tid < 256) {
      float gsum[4];
      #pragma unroll
      for (int g = 0; g < 4; ++g) {
        const int rt = g * 4 + jj2;
        float ssum = 0.0f;
        #pragma unroll
        for (int q = 0; q < 8; ++q) ssum += GPX(q, rt, cb);
        gsum[g] = ssum;
      }
      float tk = ptok[cb];
      float pi = gsum[0] + bd0 + tk * ds0;
      float pf = gsum[1] + bd1 + tk * ds1;
      float pg = gsum[2] + bd2 + tk * ds2;
      float po = gsum[3] + bd3 + tk * ds3;
      float co = g_cst[(size_t)j2 * BB + cb];
      float cn = sigf(pf) * co + sigf(pi) * tanhf(pg);
      float hv = sigf(po) * tanhf(cn);
      g_cst[(size_t)j2 * BB + cb] = cn;
      stc1(&hn[(size_t)j2 * BB + cb], hv);
    }
    bar_arrive(blk); ++sync_no; bar_wait(sync_no, &bflag);
    { float* tmp = (float*)hc; hc = hn; hn = tmp; }   // hc = new h

    // ---- D2: logits (blocks 0..127), register-direct, no LDS staging ----
    if (blk < 128) {
      float facc[4][4];
      #pragma unroll
      for (int r = 0; r < 4; ++r)
        #pragma unroll
        for (int c = 0; c < 4; ++c) facc[r][c] = 0.0f;

      LOADD2(Rs[0], hc, 0); LOADD2(Rs[1], hc, 1);
      LOADD2(Rs[2], hc, 2); LOADD2(Rs[3], hc, 3);
      for (int cb4 = 0; cb4 < 3; ++cb4) {
        const int cc = cb4 * 4;
        FMA_D2(Rs[0], cc);     LOADD2(Rs[0], hc, cc + 4);
        FMA_D2(Rs[1], cc + 1); LOADD2(Rs[1], hc, cc + 5);
        FMA_D2(Rs[2], cc + 2); LOADD2(Rs[2], hc, cc + 6);
        FMA_D2(Rs[3], cc + 3); LOADD2(Rs[3], hc, cc + 7);
      }
      FMA_D2(Rs[0], 12); FMA_D2(Rs[1], 13); FMA_D2(Rs[2], 14); FMA_D2(Rs[3], 15);

      // K-split partials (wave-private rows of Gpd alias Su; As is dead)
      #pragma unroll
      for (int r = 0; r < 4; ++r) {
        float4 v = {facc[r][0], facc[r][1], facc[r][2], facc[r][3]};
        *(float4*)&Su[ktd * 272 + r * 68 + lc4 * 4] = v;
      }
      __syncthreads();
      if (tid < 256) {
        const int oo = tid >> 6, ob = tid & 63;
        float ssum = 0.0f;
        #pragma unroll
        for (int q = 0; q < 32; ++q) ssum += Su[q * 272 + oo * 68 + ob];
        const int o = blk * 4 + oo;
        stc1(&g_logits[(size_t)o * BB + ob], ssum + fcb[o]);
      }
    }
    // prefetch next D1 chunks 0..3 (hc unchanged through argmax)
    LOADC_H(Rs[0], hc);
    LOADC_H(Rs[1], hc + (size_t)KT * BB);
    LOADC_H(Rs[2], hc + (size_t)2 * KT * BB);
    LOADC_H(Rs[3], hc + (size_t)3 * KT * BB);
    bar_arrive(blk); ++sync_no; bar_wait(sync_no, &bflag);

    // ---- argmax (redundant per block; first-index tie-break) ----
    {
      const int q = tid >> 6, b = tid & 63;
      float bv = -3.402823466e38f; int bo = 0;
      #pragma unroll
      for (int g = 0; g < 4; ++g) {
        float lv[16];
        #pragma unroll
        for (int i = 0; i < 16; ++i)
          lv[i] = ldc1(&g_logits[(size_t)(q * 64 + g * 16 + i) * BB + b]);
        #pragma unroll
        for (int i = 0; i < 16; ++i)
          if (lv[i] > bv) { bv = lv[i]; bo = q * 64 + g * 16 + i; }
      }
      avals[q][b] = bv; aidx[q][b] = bo;
    }
    __syncthreads();
    if (tid < BB) {
      float bv = avals[0][tid]; int bo = aidx[0][tid];
      #pragma unroll
      for (int q = 1; q < 8; ++q)
        if (avals[q][tid] > bv) { bv = avals[q][tid]; bo = aidx[q][tid]; }
      ptok[tid] = (float)bo;
      if (blk == 0) out[(size_t)tid * NSTEPS + s] = bo;
    }
    __syncthreads();
  }
}

extern "C" void kernel_launch(void* const* d_in, const int* in_sizes, int n_in,
                              void* d_out, int out_size, void* d_ws, size_t ws_size,
                              hipStream_t stream) {
  (void)in_sizes; (void)n_in; (void)out_size; (void)d_ws; (void)ws_size;
  const float* xin  = (const float*)d_in[0];
  const float* eWih = (const float*)d_in[1];
  const float* eWhh = (const float*)d_in[2];
  const float* ebih = (const float*)d_in[3];
  const float* ebhh = (const float*)d_in[4];
  const float* dWih = (const float*)d_in[5];
  const float* dWhh = (const float*)d_in[6];
  const float* dbih = (const float*)d_in[7];
  const float* dbhh = (const float*)d_in[8];
  const float* fcW  = (const float*)d_in[9];
  const float* fcb  = (const float*)d_in[10];
  int* out = (int*)d_out;

  reset_counter<<<1, 128, 0, stream>>>();
  seq2seq_kernel<<<NBLK, NTHR, 0, stream>>>(
      xin, eWih, eWhh, ebih, ebhh, dWih, dWhh, dbih, dbhh, fcW, fcb, out);
}